// Round 1
// baseline (275.499 us; speedup 1.0000x reference)
//
#include <hip/hip_runtime.h>
#include <math.h>

#define RENDER 256
#define IMG_H 480
#define IMG_W 640
#define NV 2048
#define NF 4096
#define FACE_SLICES 8
#define FACES_PER_SLICE (NF / FACE_SLICES)

#define SIGMA_INV 2.0f                    // 1/SIGMA, SIGMA=0.5
#define CAP 13.815510557964274f           // -log(1e-6)
#define LOG2E 1.4426950408889634f
#define LN2 0.6931471805599453f

// ws layout:
//   [0, 16KB)            xy     : 2048*2 floats (projected verts, render px)
//   [16KB, 208KB)        fdata  : 4096 faces * 12 floats (3 edges * {A,B,C,pad})
//   [208KB, 464KB)       logp   : 65536 floats
#define WS_XY_OFF    0
#define WS_FD_OFF    (16 * 1024)
#define WS_LOGP_OFF  (208 * 1024)

// ---------------- kernel 1: SE3 exp + vertex transform/projection --------
__global__ __launch_bounds__(256) void k_setup(const float* __restrict__ dof,
                                               const float* __restrict__ verts,
                                               const float* __restrict__ Km,
                                               float* __restrict__ xy) {
    __shared__ float sRt[12];   // R row-major (9) + t (3)
    if (threadIdx.x == 0) {
        float v0 = dof[0], v1 = dof[1], v2 = dof[2];
        float w0 = dof[3], w1 = dof[4], w2 = dof[5];
        float th2 = w0 * w0 + w1 * w1 + w2 * w2;
        float th = sqrtf(th2 + 1e-30f);
        bool small = th < 1e-4f;
        float th_s = small ? 1.0f : th;
        float th2_s = small ? 1.0f : th2;
        float A = small ? (1.0f - th2 / 6.0f) : (sinf(th_s) / th_s);
        float B = small ? (0.5f - th2 / 24.0f) : ((1.0f - cosf(th_s)) / th2_s);
        float C = small ? (1.0f / 6.0f - th2 / 120.0f)
                        : ((th_s - sinf(th_s)) / (th2_s * th_s));
        float Kx[9] = {0.0f, -w2, w1, w2, 0.0f, -w0, -w1, w0, 0.0f};
        float w[3] = {w0, w1, w2};
        float K2[9];
        for (int i = 0; i < 3; i++)
            for (int j = 0; j < 3; j++)
                K2[i * 3 + j] = w[i] * w[j] - (i == j ? th2 : 0.0f);
        float R[9], V[9];
        for (int i = 0; i < 9; i++) {
            float id = (i % 4 == 0) ? 1.0f : 0.0f;
            R[i] = id + A * Kx[i] + B * K2[i];
            V[i] = id + B * Kx[i] + C * K2[i];
        }
        for (int i = 0; i < 9; i++) sRt[i] = R[i];
        sRt[9]  = V[0] * v0 + V[1] * v1 + V[2] * v2;
        sRt[10] = V[3] * v0 + V[4] * v1 + V[5] * v2;
        sRt[11] = V[6] * v0 + V[7] * v1 + V[8] * v2;
    }
    __syncthreads();
    float R0 = sRt[0], R1 = sRt[1], R2 = sRt[2];
    float R3 = sRt[3], R4 = sRt[4], R5 = sRt[5];
    float R6 = sRt[6], R7 = sRt[7], R8 = sRt[8];
    float t0 = sRt[9], t1 = sRt[10], t2 = sRt[11];
    float K00 = Km[0], K01 = Km[1], K02 = Km[2];
    float K10 = Km[3], K11 = Km[4], K12 = Km[5];
    float K20 = Km[6], K21 = Km[7], K22 = Km[8];
    const float scale = 256.0f / 640.0f;
    for (int n = threadIdx.x; n < NV; n += 256) {
        float vx = verts[n * 3], vy = verts[n * 3 + 1], vz = verts[n * 3 + 2];
        float cx = R0 * vx + R1 * vy + R2 * vz + t0;
        float cy = R3 * vx + R4 * vy + R5 * vz + t1;
        float cz = R6 * vx + R7 * vy + R8 * vz + t2;
        float u = K00 * cx + K01 * cy + K02 * cz;
        float v = K10 * cx + K11 * cy + K12 * cz;
        float ww = K20 * cx + K21 * cy + K22 * cz;
        xy[n * 2]     = u / ww * scale;
        xy[n * 2 + 1] = v / ww * scale;
    }
}

// ---------------- kernel 2: per-face edge coefficients -------------------
// d_k(px,py) = A_k*py + B_k*px + C_k   (sgn and 1/elen folded in)
__global__ __launch_bounds__(256) void k_faces(const int* __restrict__ faces,
                                               const float* __restrict__ xy,
                                               float* __restrict__ fdata) {
    int f = blockIdx.x * 256 + threadIdx.x;
    if (f >= NF) return;
    int i0 = faces[f * 3], i1 = faces[f * 3 + 1], i2 = faces[f * 3 + 2];
    float x0 = xy[i0 * 2], y0 = xy[i0 * 2 + 1];
    float x1 = xy[i1 * 2], y1 = xy[i1 * 2 + 1];
    float x2 = xy[i2 * 2], y2 = xy[i2 * 2 + 1];
    float ex[3] = {x1 - x0, x2 - x1, x0 - x2};
    float ey[3] = {y1 - y0, y2 - y1, y0 - y2};
    float ax[3] = {x0, x1, x2};
    float ay[3] = {y0, y1, y2};
    // area2 = cross2(e0, -e2)
    float area2 = ex[0] * (-ey[2]) - ey[0] * (-ex[2]);
    float sgn = (area2 >= 0.0f) ? 1.0f : -1.0f;
    float* o = fdata + f * 12;
    for (int k = 0; k < 3; k++) {
        float elen = sqrtf(ex[k] * ex[k] + ey[k] * ey[k]) + 1e-9f;
        float c0 = ex[k] * ay[k] - ey[k] * ax[k];
        float inv = sgn / elen;
        o[k * 4 + 0] = ex[k] * inv;     // A (py coeff)
        o[k * 4 + 1] = -ey[k] * inv;    // B (px coeff)
        o[k * 4 + 2] = -c0 * inv;       // C
        o[k * 4 + 3] = 0.0f;
    }
}

// ---------------- kernel 3: soft rasterization ---------------------------
// grid.x = 256 pixel-blocks (one image row each), grid.y = FACE_SLICES
__global__ __launch_bounds__(256) void k_raster(const float* __restrict__ fdata,
                                                float* __restrict__ logp) {
    int p = blockIdx.x * 256 + threadIdx.x;
    float px = (float)(p & (RENDER - 1)) + 0.5f;
    float py = (float)(p >> 8) + 0.5f;
    const float4* __restrict__ fd =
        (const float4*)fdata + (size_t)blockIdx.y * FACES_PER_SLICE * 3;
    float acc = 0.0f;
    for (int i = 0; i < FACES_PER_SLICE; ++i) {
        float4 e0 = fd[i * 3 + 0];
        float4 e1 = fd[i * 3 + 1];
        float4 e2 = fd[i * 3 + 2];
        float d0 = fmaf(e0.y, px, fmaf(e0.x, py, e0.z));
        float d1 = fmaf(e1.y, px, fmaf(e1.x, py, e1.z));
        float d2 = fmaf(e2.y, px, fmaf(e2.x, py, e2.z));
        float dmin = fminf(d0, fminf(d1, d2));
        float z = dmin * SIGMA_INV;
        // log1p(-min(sigmoid(z), 1-1e-6)) == -min(softplus(z), CAP)
        float e = exp2f(z * LOG2E);
        float sp = log2f(1.0f + e) * LN2;   // +inf for huge z -> capped below
        acc -= fminf(sp, CAP);
    }
    atomicAdd(&logp[p], acc);
}

// ---------------- kernel 4: resize-nearest + crop + SSE loss -------------
__global__ __launch_bounds__(256) void k_final(const float* __restrict__ logp,
                                               const float* __restrict__ mask,
                                               float* __restrict__ out) {
    int idx = blockIdx.x * 256 + threadIdx.x;   // 0 .. 307199
    int r = idx / IMG_W;
    int c = idx - r * IMG_W;
    // jax nearest: in = floor((out+0.5)*256/640) == (2*out+1)/5 exactly
    int ir = (2 * r + 1) / 5;
    int ic = (2 * c + 1) / 5;
    float si = 1.0f - expf(logp[ir * RENDER + ic]);
    out[1 + idx] = si;
    float diff = si - mask[idx];
    float d2 = diff * diff;
    #pragma unroll
    for (int off = 32; off > 0; off >>= 1) d2 += __shfl_down(d2, off, 64);
    __shared__ float sred[4];
    int lane = threadIdx.x & 63;
    int wv = threadIdx.x >> 6;
    if (lane == 0) sred[wv] = d2;
    __syncthreads();
    if (threadIdx.x == 0)
        atomicAdd(out, sred[0] + sred[1] + sred[2] + sred[3]);
}

extern "C" void kernel_launch(void* const* d_in, const int* in_sizes, int n_in,
                              void* d_out, int out_size, void* d_ws, size_t ws_size,
                              hipStream_t stream) {
    const float* dof   = (const float*)d_in[0];
    const float* verts = (const float*)d_in[1];
    const int*   faces = (const int*)d_in[2];
    const float* Km    = (const float*)d_in[3];
    const float* mask  = (const float*)d_in[4];
    float* out = (float*)d_out;

    char* ws = (char*)d_ws;
    float* xy    = (float*)(ws + WS_XY_OFF);
    float* fdata = (float*)(ws + WS_FD_OFF);
    float* logp  = (float*)(ws + WS_LOGP_OFF);

    hipMemsetAsync(logp, 0, RENDER * RENDER * sizeof(float), stream);
    hipMemsetAsync(out, 0, sizeof(float), stream);

    k_setup<<<1, 256, 0, stream>>>(dof, verts, Km, xy);
    k_faces<<<NF / 256, 256, 0, stream>>>(faces, xy, fdata);
    k_raster<<<dim3(RENDER * RENDER / 256, FACE_SLICES), 256, 0, stream>>>(fdata, logp);
    k_final<<<IMG_H * IMG_W / 256, 256, 0, stream>>>(logp, mask, out);
}

// Round 2
// 208.658 us; speedup vs baseline: 1.3203x; 1.3203x over previous
//
#include <hip/hip_runtime.h>
#include <math.h>

#define RENDER 256
#define IMG_H 480
#define IMG_W 640
#define NV 2048
#define NF 4096
#define FACE_SLICES 8
#define FACES_PER_SLICE (NF / FACE_SLICES)

#define SIGMA_INV 2.0f                    // 1/SIGMA, SIGMA=0.5
#define CAP 13.815510557964274f           // -log(1e-6)
#define LOG2E 1.4426950408889634f
#define LN2 0.6931471805599453f
// tile half-diagonal for 16x16 pixel centers: 7.5*sqrt(2)
#define TILE_RAD 10.6066f
// dmin_c thresholds (see analysis): capped if > CAP/2 + RAD (+margin),
// skip if < -(8.85 + RAD) (+margin)
#define THR_CAP  17.6f
#define THR_SKIP -19.6f

// ws layout:
//   [0, 16KB)            xy     : 2048*2 floats (projected verts, render px)
//   [16KB, 208KB)        fdata  : 4096 faces * 12 floats (3 edges * {A,B,C,pad})
//   [208KB, 464KB)       logp   : 65536 floats
#define WS_XY_OFF    0
#define WS_FD_OFF    (16 * 1024)
#define WS_LOGP_OFF  (208 * 1024)

// ---------------- kernel 1: SE3 exp + vertex transform/projection --------
__global__ __launch_bounds__(256) void k_setup(const float* __restrict__ dof,
                                               const float* __restrict__ verts,
                                               const float* __restrict__ Km,
                                               float* __restrict__ xy) {
    __shared__ float sRt[12];   // R row-major (9) + t (3)
    if (threadIdx.x == 0) {
        float v0 = dof[0], v1 = dof[1], v2 = dof[2];
        float w0 = dof[3], w1 = dof[4], w2 = dof[5];
        float th2 = w0 * w0 + w1 * w1 + w2 * w2;
        float th = sqrtf(th2 + 1e-30f);
        bool small = th < 1e-4f;
        float th_s = small ? 1.0f : th;
        float th2_s = small ? 1.0f : th2;
        float A = small ? (1.0f - th2 / 6.0f) : (sinf(th_s) / th_s);
        float B = small ? (0.5f - th2 / 24.0f) : ((1.0f - cosf(th_s)) / th2_s);
        float C = small ? (1.0f / 6.0f - th2 / 120.0f)
                        : ((th_s - sinf(th_s)) / (th2_s * th_s));
        float Kx[9] = {0.0f, -w2, w1, w2, 0.0f, -w0, -w1, w0, 0.0f};
        float w[3] = {w0, w1, w2};
        float K2[9];
        for (int i = 0; i < 3; i++)
            for (int j = 0; j < 3; j++)
                K2[i * 3 + j] = w[i] * w[j] - (i == j ? th2 : 0.0f);
        float R[9], V[9];
        for (int i = 0; i < 9; i++) {
            float id = (i % 4 == 0) ? 1.0f : 0.0f;
            R[i] = id + A * Kx[i] + B * K2[i];
            V[i] = id + B * Kx[i] + C * K2[i];
        }
        for (int i = 0; i < 9; i++) sRt[i] = R[i];
        sRt[9]  = V[0] * v0 + V[1] * v1 + V[2] * v2;
        sRt[10] = V[3] * v0 + V[4] * v1 + V[5] * v2;
        sRt[11] = V[6] * v0 + V[7] * v1 + V[8] * v2;
    }
    __syncthreads();
    float R0 = sRt[0], R1 = sRt[1], R2 = sRt[2];
    float R3 = sRt[3], R4 = sRt[4], R5 = sRt[5];
    float R6 = sRt[6], R7 = sRt[7], R8 = sRt[8];
    float t0 = sRt[9], t1 = sRt[10], t2 = sRt[11];
    float K00 = Km[0], K01 = Km[1], K02 = Km[2];
    float K10 = Km[3], K11 = Km[4], K12 = Km[5];
    float K20 = Km[6], K21 = Km[7], K22 = Km[8];
    const float scale = 256.0f / 640.0f;
    for (int n = threadIdx.x; n < NV; n += 256) {
        float vx = verts[n * 3], vy = verts[n * 3 + 1], vz = verts[n * 3 + 2];
        float cx = R0 * vx + R1 * vy + R2 * vz + t0;
        float cy = R3 * vx + R4 * vy + R5 * vz + t1;
        float cz = R6 * vx + R7 * vy + R8 * vz + t2;
        float u = K00 * cx + K01 * cy + K02 * cz;
        float v = K10 * cx + K11 * cy + K12 * cz;
        float ww = K20 * cx + K21 * cy + K22 * cz;
        xy[n * 2]     = u / ww * scale;
        xy[n * 2 + 1] = v / ww * scale;
    }
}

// ---------------- kernel 2: per-face edge coefficients -------------------
// d_k(px,py) = A_k*py + B_k*px + C_k   (sgn and 1/elen folded in)
__global__ __launch_bounds__(256) void k_faces(const int* __restrict__ faces,
                                               const float* __restrict__ xy,
                                               float* __restrict__ fdata) {
    int f = blockIdx.x * 256 + threadIdx.x;
    if (f >= NF) return;
    int i0 = faces[f * 3], i1 = faces[f * 3 + 1], i2 = faces[f * 3 + 2];
    float x0 = xy[i0 * 2], y0 = xy[i0 * 2 + 1];
    float x1 = xy[i1 * 2], y1 = xy[i1 * 2 + 1];
    float x2 = xy[i2 * 2], y2 = xy[i2 * 2 + 1];
    float ex[3] = {x1 - x0, x2 - x1, x0 - x2};
    float ey[3] = {y1 - y0, y2 - y1, y0 - y2};
    float ax[3] = {x0, x1, x2};
    float ay[3] = {y0, y1, y2};
    // area2 = cross2(e0, -e2)
    float area2 = ex[0] * (-ey[2]) - ey[0] * (-ex[2]);
    float sgn = (area2 >= 0.0f) ? 1.0f : -1.0f;
    float* o = fdata + f * 12;
    for (int k = 0; k < 3; k++) {
        float elen = sqrtf(ex[k] * ex[k] + ey[k] * ey[k]) + 1e-9f;
        float c0 = ex[k] * ay[k] - ey[k] * ax[k];
        float inv = sgn / elen;
        o[k * 4 + 0] = ex[k] * inv;     // A (py coeff)
        o[k * 4 + 1] = -ey[k] * inv;    // B (px coeff)
        o[k * 4 + 2] = -c0 * inv;       // C
        o[k * 4 + 3] = 0.0f;
    }
}

// ---------------- kernel 3: tiled + culled soft rasterization ------------
// block = 256 threads = one 16x16 pixel tile; grid.x = 256 tiles,
// grid.y = FACE_SLICES face slices.
// Phase 1: each thread classifies faces of the slice at the tile center
//          (dmin is 1-Lipschitz: min of affine funcs w/ |grad|<1).
// Phase 2: full eval of survivor list only.
__global__ __launch_bounds__(256) void k_raster(const float* __restrict__ fdata,
                                                float* __restrict__ logp) {
    __shared__ int s_list[FACES_PER_SLICE];
    __shared__ int s_n;
    __shared__ int s_ncap;
    const int tid = threadIdx.x;
    if (tid == 0) { s_n = 0; s_ncap = 0; }
    __syncthreads();

    const int tileX = blockIdx.x & 15;
    const int tileY = blockIdx.x >> 4;
    const float cx = tileX * 16 + 8.0f;   // center of pixel-center extent
    const float cy = tileY * 16 + 8.0f;

    const int slice_base = blockIdx.y * FACES_PER_SLICE;
    const float4* __restrict__ fd4 = (const float4*)fdata;

    // ---- phase 1: cull (one face per thread) ----
    for (int r = 0; r < FACES_PER_SLICE / 256; ++r) {
        int f = slice_base + r * 256 + tid;
        float4 e0 = fd4[f * 3 + 0];
        float4 e1 = fd4[f * 3 + 1];
        float4 e2 = fd4[f * 3 + 2];
        float d0 = fmaf(e0.y, cx, fmaf(e0.x, cy, e0.z));
        float d1 = fmaf(e1.y, cx, fmaf(e1.x, cy, e1.z));
        float d2 = fmaf(e2.y, cx, fmaf(e2.x, cy, e2.z));
        float dmin = fminf(d0, fminf(d1, d2));
        if (dmin > THR_CAP) {
            atomicAdd(&s_ncap, 1);
        } else if (dmin > THR_SKIP) {
            int k = atomicAdd(&s_n, 1);
            s_list[k] = f;
        }
    }
    __syncthreads();

    // ---- phase 2: full eval of survivors ----
    const int ix = tileX * 16 + (tid & 15);
    const int iy = tileY * 16 + (tid >> 4);
    const float px = (float)ix + 0.5f;
    const float py = (float)iy + 0.5f;

    float acc = -CAP * (float)s_ncap;
    const int n = s_n;
    const float ZK = SIGMA_INV * LOG2E;   // dmin -> log2-domain exponent
    for (int i = 0; i < n; ++i) {
        int f = __builtin_amdgcn_readfirstlane(s_list[i]);
        float4 e0 = fd4[f * 3 + 0];
        float4 e1 = fd4[f * 3 + 1];
        float4 e2 = fd4[f * 3 + 2];
        float d0 = fmaf(e0.y, px, fmaf(e0.x, py, e0.z));
        float d1 = fmaf(e1.y, px, fmaf(e1.x, py, e1.z));
        float d2 = fmaf(e2.y, px, fmaf(e2.x, py, e2.z));
        float dmin = fminf(d0, fminf(d1, d2));
        // -log1p(-min(sigmoid(2*dmin),1-1e-6)) == min(softplus(2*dmin), CAP)
        float e = __builtin_amdgcn_exp2f(dmin * ZK);
        float sp = __builtin_amdgcn_logf(1.0f + e) * LN2;  // v_log_f32 = log2
        acc -= fminf(sp, CAP);
    }
    atomicAdd(&logp[iy * RENDER + ix], acc);
}

// ---------------- kernel 4: resize-nearest + crop + SSE loss -------------
__global__ __launch_bounds__(256) void k_final(const float* __restrict__ logp,
                                               const float* __restrict__ mask,
                                               float* __restrict__ out) {
    int idx = blockIdx.x * 256 + threadIdx.x;   // 0 .. 307199
    int r = idx / IMG_W;
    int c = idx - r * IMG_W;
    // jax nearest: in = floor((out+0.5)*256/640) == (2*out+1)/5 exactly
    int ir = (2 * r + 1) / 5;
    int ic = (2 * c + 1) / 5;
    float si = 1.0f - expf(logp[ir * RENDER + ic]);
    out[1 + idx] = si;
    float diff = si - mask[idx];
    float d2 = diff * diff;
    #pragma unroll
    for (int off = 32; off > 0; off >>= 1) d2 += __shfl_down(d2, off, 64);
    __shared__ float sred[4];
    int lane = threadIdx.x & 63;
    int wv = threadIdx.x >> 6;
    if (lane == 0) sred[wv] = d2;
    __syncthreads();
    if (threadIdx.x == 0)
        atomicAdd(out, sred[0] + sred[1] + sred[2] + sred[3]);
}

extern "C" void kernel_launch(void* const* d_in, const int* in_sizes, int n_in,
                              void* d_out, int out_size, void* d_ws, size_t ws_size,
                              hipStream_t stream) {
    const float* dof   = (const float*)d_in[0];
    const float* verts = (const float*)d_in[1];
    const int*   faces = (const int*)d_in[2];
    const float* Km    = (const float*)d_in[3];
    const float* mask  = (const float*)d_in[4];
    float* out = (float*)d_out;

    char* ws = (char*)d_ws;
    float* xy    = (float*)(ws + WS_XY_OFF);
    float* fdata = (float*)(ws + WS_FD_OFF);
    float* logp  = (float*)(ws + WS_LOGP_OFF);

    hipMemsetAsync(logp, 0, RENDER * RENDER * sizeof(float), stream);
    hipMemsetAsync(out, 0, sizeof(float), stream);

    k_setup<<<1, 256, 0, stream>>>(dof, verts, Km, xy);
    k_faces<<<NF / 256, 256, 0, stream>>>(faces, xy, fdata);
    k_raster<<<dim3(RENDER * RENDER / 256, FACE_SLICES), 256, 0, stream>>>(fdata, logp);
    k_final<<<IMG_H * IMG_W / 256, 256, 0, stream>>>(logp, mask, out);
}

// Round 3
// 160.947 us; speedup vs baseline: 1.7117x; 1.2964x over previous
//
#include <hip/hip_runtime.h>
#include <math.h>

#define RENDER 256
#define IMG_H 480
#define IMG_W 640
#define NV 2048
#define NF 4096
#define FACE_SLICES 16
#define FACES_PER_SLICE (NF / FACE_SLICES)   // 256

#define SIGMA_INV 2.0f                    // 1/SIGMA, SIGMA=0.5
#define CAP 13.815510557964274f           // -log(1e-6)
#define LOG2E 1.4426950408889634f
#define LN2 0.6931471805599453f
// 16x16 pixel tile, half-diagonal of pixel centers = 7.5*sqrt(2) = 10.607
// dmin is 1-Lipschitz (min of affine funcs with |grad|<=1):
//   capped everywhere if dmin_center > CAP/2 + rad (+margin)
//   negligible (<2e-8/face) if dmin_center < -(8.85 + rad) (+margin)
#define THR_CAP  17.6f
#define THR_SKIP -19.6f

// ws layout:
//   [0, 192KB)       fdata : 4096 faces * 12 floats (3 edges * {A,B,C,pad})
//   [192KB, 448KB)   logp  : 65536 floats
#define WS_FD_OFF    0
#define WS_LOGP_OFF  (192 * 1024)

// ---------------- kernel 1: fused setup ----------------------------------
// blocks 0..15   : SE3 exp (per-thread redundant) + project all verts into
//                  LDS (redundant per block) + per-face edge coefficients
// blocks 16..271 : zero logp (1 float/thread); block 16 also zeros out[0]
__global__ __launch_bounds__(256) void k_prep(const float* __restrict__ dof,
                                              const float* __restrict__ verts,
                                              const int* __restrict__ faces,
                                              const float* __restrict__ Km,
                                              float* __restrict__ fdata,
                                              float* __restrict__ logp,
                                              float* __restrict__ out) {
    if (blockIdx.x >= 16) {
        int i = (blockIdx.x - 16) * 256 + threadIdx.x;
        logp[i] = 0.0f;
        if (blockIdx.x == 16 && threadIdx.x == 0) out[0] = 0.0f;
        return;
    }

    __shared__ float sxy[NV * 2];   // 16 KB projected verts

    // --- SE3 exp, computed redundantly per thread (cheap, no barrier) ---
    float v0 = dof[0], v1 = dof[1], v2 = dof[2];
    float w0 = dof[3], w1 = dof[4], w2 = dof[5];
    float th2 = w0 * w0 + w1 * w1 + w2 * w2;
    float th = sqrtf(th2 + 1e-30f);
    bool small = th < 1e-4f;
    float th_s = small ? 1.0f : th;
    float th2_s = small ? 1.0f : th2;
    float A = small ? (1.0f - th2 / 6.0f) : (sinf(th_s) / th_s);
    float B = small ? (0.5f - th2 / 24.0f) : ((1.0f - cosf(th_s)) / th2_s);
    float C = small ? (1.0f / 6.0f - th2 / 120.0f)
                    : ((th_s - sinf(th_s)) / (th2_s * th_s));
    float Kx[9] = {0.0f, -w2, w1, w2, 0.0f, -w0, -w1, w0, 0.0f};
    float w[3] = {w0, w1, w2};
    float R[9], V[9];
    for (int i = 0; i < 3; i++)
        for (int j = 0; j < 3; j++) {
            float K2 = w[i] * w[j] - (i == j ? th2 : 0.0f);
            float id = (i == j) ? 1.0f : 0.0f;
            R[i * 3 + j] = id + A * Kx[i * 3 + j] + B * K2;
            V[i * 3 + j] = id + B * Kx[i * 3 + j] + C * K2;
        }
    float t0 = V[0] * v0 + V[1] * v1 + V[2] * v2;
    float t1 = V[3] * v0 + V[4] * v1 + V[5] * v2;
    float t2 = V[6] * v0 + V[7] * v1 + V[8] * v2;
    float K00 = Km[0], K01 = Km[1], K02 = Km[2];
    float K10 = Km[3], K11 = Km[4], K12 = Km[5];
    float K20 = Km[6], K21 = Km[7], K22 = Km[8];
    const float scale = 256.0f / 640.0f;

    for (int n = threadIdx.x; n < NV; n += 256) {
        float vx = verts[n * 3], vy = verts[n * 3 + 1], vz = verts[n * 3 + 2];
        float cx = R[0] * vx + R[1] * vy + R[2] * vz + t0;
        float cy = R[3] * vx + R[4] * vy + R[5] * vz + t1;
        float cz = R[6] * vx + R[7] * vy + R[8] * vz + t2;
        float u = K00 * cx + K01 * cy + K02 * cz;
        float v = K10 * cx + K11 * cy + K12 * cz;
        float ww = K20 * cx + K21 * cy + K22 * cz;
        sxy[n * 2]     = u / ww * scale;
        sxy[n * 2 + 1] = v / ww * scale;
    }
    __syncthreads();

    // --- one face per thread ---
    int f = blockIdx.x * 256 + threadIdx.x;
    int i0 = faces[f * 3], i1 = faces[f * 3 + 1], i2 = faces[f * 3 + 2];
    float x0 = sxy[i0 * 2], y0 = sxy[i0 * 2 + 1];
    float x1 = sxy[i1 * 2], y1 = sxy[i1 * 2 + 1];
    float x2 = sxy[i2 * 2], y2 = sxy[i2 * 2 + 1];
    float ex[3] = {x1 - x0, x2 - x1, x0 - x2};
    float ey[3] = {y1 - y0, y2 - y1, y0 - y2};
    float ax[3] = {x0, x1, x2};
    float ay[3] = {y0, y1, y2};
    float area2 = ex[0] * (-ey[2]) - ey[0] * (-ex[2]);
    float sgn = (area2 >= 0.0f) ? 1.0f : -1.0f;
    float* o = fdata + f * 12;
    for (int k = 0; k < 3; k++) {
        float elen = sqrtf(ex[k] * ex[k] + ey[k] * ey[k]) + 1e-9f;
        float c0 = ex[k] * ay[k] - ey[k] * ax[k];
        float inv = sgn / elen;
        o[k * 4 + 0] = ex[k] * inv;     // A (py coeff)
        o[k * 4 + 1] = -ey[k] * inv;    // B (px coeff)
        o[k * 4 + 2] = -c0 * inv;       // C
        o[k * 4 + 3] = 0.0f;
    }
}

// ---------------- kernel 2: tiled + culled soft rasterization ------------
// block = 256 threads = one 16x16 pixel tile; grid = (256 tiles, 16 slices).
// Phase 1: classify the slice's 256 faces at the tile center (1/thread),
//          ballot-compact survivors' coefficient data into LDS.
// Phase 2: all threads evaluate only the LDS survivor list (broadcast reads).
__global__ __launch_bounds__(256) void k_raster(const float* __restrict__ fdata,
                                                float* __restrict__ logp) {
    __shared__ float s_data[FACES_PER_SLICE * 12];   // 12 KB survivor coeffs
    __shared__ int s_n;
    __shared__ int s_ncap;
    const int tid = threadIdx.x;
    if (tid == 0) { s_n = 0; s_ncap = 0; }
    __syncthreads();

    const int tileX = blockIdx.x & 15;
    const int tileY = blockIdx.x >> 4;
    const float cx = tileX * 16 + 8.0f;
    const float cy = tileY * 16 + 8.0f;

    const float4* __restrict__ fd4 = (const float4*)fdata;

    // ---- phase 1: cull + compact (one face per thread) ----
    {
        int f = blockIdx.y * FACES_PER_SLICE + tid;
        float4 e0 = fd4[f * 3 + 0];
        float4 e1 = fd4[f * 3 + 1];
        float4 e2 = fd4[f * 3 + 2];
        float d0 = fmaf(e0.y, cx, fmaf(e0.x, cy, e0.z));
        float d1 = fmaf(e1.y, cx, fmaf(e1.x, cy, e1.z));
        float d2 = fmaf(e2.y, cx, fmaf(e2.x, cy, e2.z));
        float dmin = fminf(d0, fminf(d1, d2));
        bool capped = dmin > THR_CAP;
        bool live = (!capped) && (dmin > THR_SKIP);
        unsigned long long mcap = __ballot(capped);
        unsigned long long mliv = __ballot(live);
        int lane = tid & 63;
        int base = 0;
        if (lane == 0) {
            base = atomicAdd(&s_n, __popcll(mliv));
            atomicAdd(&s_ncap, __popcll(mcap));
        }
        base = __shfl(base, 0, 64);
        if (live) {
            int pos = base + __popcll(mliv & ((1ull << lane) - 1ull));
            float4* dst = (float4*)(s_data + pos * 12);   // 48B-aligned
            dst[0] = e0; dst[1] = e1; dst[2] = e2;
        }
    }
    __syncthreads();

    // ---- phase 2: evaluate survivors from LDS (broadcast reads) ----
    const int ix = tileX * 16 + (tid & 15);
    const int iy = tileY * 16 + (tid >> 4);
    const float px = (float)ix + 0.5f;
    const float py = (float)iy + 0.5f;

    float acc = -CAP * (float)s_ncap;
    const int n = s_n;
    const float4* sd = (const float4*)s_data;
    const float ZK = SIGMA_INV * LOG2E;
    #pragma unroll 2
    for (int i = 0; i < n; ++i) {
        float4 e0 = sd[i * 3 + 0];
        float4 e1 = sd[i * 3 + 1];
        float4 e2 = sd[i * 3 + 2];
        float d0 = fmaf(e0.y, px, fmaf(e0.x, py, e0.z));
        float d1 = fmaf(e1.y, px, fmaf(e1.x, py, e1.z));
        float d2 = fmaf(e2.y, px, fmaf(e2.x, py, e2.z));
        float dmin = fminf(d0, fminf(d1, d2));
        // -log1p(-min(sigmoid(2*dmin),1-1e-6)) == min(softplus(2*dmin), CAP)
        float e = __builtin_amdgcn_exp2f(dmin * ZK);
        float sp = __builtin_amdgcn_logf(1.0f + e) * LN2;   // v_log_f32 = log2
        acc -= fminf(sp, CAP);
    }
    atomicAdd(&logp[iy * RENDER + ix], acc);
}

// ---------------- kernel 3: resize-nearest + crop + SSE loss -------------
__global__ __launch_bounds__(256) void k_final(const float* __restrict__ logp,
                                               const float* __restrict__ mask,
                                               float* __restrict__ out) {
    int idx = blockIdx.x * 256 + threadIdx.x;   // 0 .. 307199
    int r = idx / IMG_W;
    int c = idx - r * IMG_W;
    // jax nearest: in = floor((out+0.5)*256/640) == (2*out+1)/5 exactly
    int ir = (2 * r + 1) / 5;
    int ic = (2 * c + 1) / 5;
    float si = 1.0f - expf(logp[ir * RENDER + ic]);
    out[1 + idx] = si;
    float diff = si - mask[idx];
    float d2 = diff * diff;
    #pragma unroll
    for (int off = 32; off > 0; off >>= 1) d2 += __shfl_down(d2, off, 64);
    __shared__ float sred[4];
    int lane = threadIdx.x & 63;
    int wv = threadIdx.x >> 6;
    if (lane == 0) sred[wv] = d2;
    __syncthreads();
    if (threadIdx.x == 0)
        atomicAdd(out, sred[0] + sred[1] + sred[2] + sred[3]);
}

extern "C" void kernel_launch(void* const* d_in, const int* in_sizes, int n_in,
                              void* d_out, int out_size, void* d_ws, size_t ws_size,
                              hipStream_t stream) {
    const float* dof   = (const float*)d_in[0];
    const float* verts = (const float*)d_in[1];
    const int*   faces = (const int*)d_in[2];
    const float* Km    = (const float*)d_in[3];
    const float* mask  = (const float*)d_in[4];
    float* out = (float*)d_out;

    char* ws = (char*)d_ws;
    float* fdata = (float*)(ws + WS_FD_OFF);
    float* logp  = (float*)(ws + WS_LOGP_OFF);

    k_prep<<<272, 256, 0, stream>>>(dof, verts, faces, Km, fdata, logp, out);
    k_raster<<<dim3(RENDER * RENDER / 256, FACE_SLICES), 256, 0, stream>>>(fdata, logp);
    k_final<<<IMG_H * IMG_W / 256, 256, 0, stream>>>(logp, mask, out);
}